// Round 2
// baseline (371.166 us; speedup 1.0000x reference)
//
#include <hip/hip_runtime.h>

// GAE backward scan, 3-phase chunked decomposition for parallelism.
// adv[t] = delta[t] + g*adv[t+1],  delta[t] = r[t] + gamma*v[t+1] - v[t],
// g = gamma*lambda.  Linear recurrence -> split T into C chunks:
//   K1: per-chunk partial scan (zero carry), partials -> out, aggregates -> ws
//   K2: per-column sequential combine of C aggregates -> per-chunk carry-in
//   K3: out[t] += g^(t_hi+1-t) * carry_in   (chunk C-1 has carry 0, skipped)
// Round-1 single-pass was latency-bound (2 waves/CU, 19% HBM BW); C=32 gives
// 32 waves/CU in K1. Partials round-trip through L3 (134 MB < 256 MiB).

#define GAE_T   1024
#define GAE_B   32768
#define GAE_T1  1023           // output rows (t = 0 .. 1022)
#define B4      (GAE_B / 4)    // 8192 float4 columns

#define GAMMA_F 0.99f
#define GL_F    0.9405f        // (float)(0.99 * 0.95)

#define GAE_STEP(r, v)                                      \
  p.x = (r).x + GAMMA_F * vn.x - (v).x + GL_F * p.x;        \
  p.y = (r).y + GAMMA_F * vn.y - (v).y + GL_F * p.y;        \
  p.z = (r).z + GAMMA_F * vn.z - (v).z + GL_F * p.z;        \
  p.w = (r).w + GAMMA_F * vn.w - (v).w + GL_F * p.w;

// ---------- K1: per-chunk backward partial scan ----------
__global__ __launch_bounds__(256) void gae_partial(
    const float4* __restrict__ r4, const float4* __restrict__ v4,
    float4* __restrict__ o4, float4* __restrict__ agg4, int S) {
  const int q = blockIdx.x * 256 + threadIdx.x;  // float4 column, 0..B4-1
  const int c = blockIdx.y;
  const int t_lo = c * S;
  int t_hi = t_lo + S - 1;
  if (t_hi > GAE_T1 - 1) t_hi = GAE_T1 - 1;

  float4 vn = v4[(t_hi + 1) * B4 + q];
  float4 p = make_float4(0.f, 0.f, 0.f, 0.f);

  int t = t_hi;
  const int pre = (t_hi - t_lo + 1) & 3;
  for (int k = 0; k < pre; ++k, --t) {
    float4 r = r4[t * B4 + q];
    float4 v = v4[t * B4 + q];
    GAE_STEP(r, v)
    o4[t * B4 + q] = p;
    vn = v;
  }
  // remaining length is a multiple of 4; batch loads 4 timesteps ahead
  for (; t >= t_lo + 3; t -= 4) {
    float4 r0 = r4[(t    ) * B4 + q], v0 = v4[(t    ) * B4 + q];
    float4 r1 = r4[(t - 1) * B4 + q], v1 = v4[(t - 1) * B4 + q];
    float4 r2 = r4[(t - 2) * B4 + q], v2 = v4[(t - 2) * B4 + q];
    float4 r3 = r4[(t - 3) * B4 + q], v3 = v4[(t - 3) * B4 + q];
    GAE_STEP(r0, v0)  o4[(t    ) * B4 + q] = p;  vn = v0;
    GAE_STEP(r1, v1)  o4[(t - 1) * B4 + q] = p;  vn = v1;
    GAE_STEP(r2, v2)  o4[(t - 2) * B4 + q] = p;  vn = v2;
    GAE_STEP(r3, v3)  o4[(t - 3) * B4 + q] = p;  vn = v3;
  }
  agg4[c * B4 + q] = p;  // aggregate: zero-carry partial at chunk start
}

// ---------- K2: per-column combine of chunk aggregates ----------
// After this, agg[c*B + b] holds the carry INTO chunk c (true adv at t_hi+1).
__global__ __launch_bounds__(256) void gae_combine(
    float* __restrict__ agg, int C, float gS) {
  const int b = blockIdx.x * 256 + threadIdx.x;  // 0..B-1
  float carry = 0.f;
#pragma unroll 8
  for (int c = C - 1; c >= 0; --c) {
    float a = agg[c * GAE_B + b];
    agg[c * GAE_B + b] = carry;
    carry = a + gS * carry;   // all combined chunks have full length S
  }
}

// ---------- K3: fix-up out[t] += g^(t_hi+1-t) * carry_in ----------
__global__ __launch_bounds__(256) void gae_fixup(
    float4* __restrict__ o4, const float4* __restrict__ carry4, int S) {
  const int q = blockIdx.x * 256 + threadIdx.x;
  const int c = blockIdx.y;          // 0..C-2 (chunk C-1 carry is 0)
  const int t_lo = c * S;
  const int t_hi = t_lo + S - 1;     // full-length chunks only, t_hi <= 1021

  float4 ci = carry4[c * B4 + q];
  float4 x = make_float4(GL_F * ci.x, GL_F * ci.y, GL_F * ci.z, GL_F * ci.w);
  for (int t = t_hi; t >= t_lo + 3; t -= 4) {   // S % 4 == 0
    float4 o0 = o4[(t    ) * B4 + q];
    float4 o1 = o4[(t - 1) * B4 + q];
    float4 o2 = o4[(t - 2) * B4 + q];
    float4 o3 = o4[(t - 3) * B4 + q];
    o0.x += x.x; o0.y += x.y; o0.z += x.z; o0.w += x.w;
    x.x *= GL_F; x.y *= GL_F; x.z *= GL_F; x.w *= GL_F;
    o1.x += x.x; o1.y += x.y; o1.z += x.z; o1.w += x.w;
    x.x *= GL_F; x.y *= GL_F; x.z *= GL_F; x.w *= GL_F;
    o2.x += x.x; o2.y += x.y; o2.z += x.z; o2.w += x.w;
    x.x *= GL_F; x.y *= GL_F; x.z *= GL_F; x.w *= GL_F;
    o3.x += x.x; o3.y += x.y; o3.z += x.z; o3.w += x.w;
    x.x *= GL_F; x.y *= GL_F; x.z *= GL_F; x.w *= GL_F;
    o4[(t    ) * B4 + q] = o0;
    o4[(t - 1) * B4 + q] = o1;
    o4[(t - 2) * B4 + q] = o2;
    o4[(t - 3) * B4 + q] = o3;
  }
}

// ---------- fallback: round-1 single-pass (if ws too small) ----------
__global__ __launch_bounds__(64) void gae_single_pass(
    const float* __restrict__ rewards, const float* __restrict__ values,
    float* __restrict__ out) {
  const int b = blockIdx.x * blockDim.x + threadIdx.x;
  const float* rp = rewards + b;
  const float* vp = values + b;
  float* op = out + b;
  float vn = vp[(GAE_T - 1) * GAE_B];
  float adv = 0.0f;
  int t = GAE_T - 2;
  for (int k = 0; k < 7; ++k, --t) {
    float v = vp[t * GAE_B], r = rp[t * GAE_B];
    adv = r + GAMMA_F * vn - v + GL_F * adv;
    op[t * GAE_B] = adv;
    vn = v;
  }
  for (; t >= 7; t -= 8) {
    float r8[8], v8[8];
#pragma unroll
    for (int k = 0; k < 8; ++k) {
      v8[k] = vp[(t - k) * GAE_B];
      r8[k] = rp[(t - k) * GAE_B];
    }
#pragma unroll
    for (int k = 0; k < 8; ++k) {
      adv = r8[k] + GAMMA_F * vn - v8[k] + GL_F * adv;
      op[(t - k) * GAE_B] = adv;
      vn = v8[k];
    }
  }
}

extern "C" void kernel_launch(void* const* d_in, const int* in_sizes, int n_in,
                              void* d_out, int out_size, void* d_ws, size_t ws_size,
                              hipStream_t stream) {
  const float* rewards = (const float*)d_in[0];
  const float* values = (const float*)d_in[1];
  float* out = (float*)d_out;

  int C = 32;
  if (ws_size < (size_t)32 * GAE_B * 4) C = 16;
  if (ws_size < (size_t)16 * GAE_B * 4) C = 8;
  if (ws_size < (size_t)8 * GAE_B * 4) {
    gae_single_pass<<<dim3(GAE_B / 64), dim3(64), 0, stream>>>(rewards, values, out);
    return;
  }
  const int S = (GAE_T1 + C - 1) / C;  // 32 / 64 / 128

  float gS = 1.f;
  for (int i = 0; i < S; ++i) gS *= GL_F;

  const float4* r4 = (const float4*)rewards;
  const float4* v4 = (const float4*)values;
  float4* o4 = (float4*)out;
  float4* agg4 = (float4*)d_ws;

  gae_partial<<<dim3(B4 / 256, C), dim3(256), 0, stream>>>(r4, v4, o4, agg4, S);
  gae_combine<<<dim3(GAE_B / 256), dim3(256), 0, stream>>>((float*)d_ws, C, gS);
  gae_fixup<<<dim3(B4 / 256, C - 1), dim3(256), 0, stream>>>(o4, agg4, S);
}

// Round 3
// 361.322 us; speedup vs baseline: 1.0272x; 1.0272x over previous
//
#include <hip/hip_runtime.h>
#include <math.h>

// GAE backward scan, single fused kernel.
//   adv[t] = delta[t] + g*adv[t+1], delta[t] = r[t] + 0.99*v[t+1] - v[t], g=0.9405
// Intra-block chunked decomposition: block = 8 waves x 64 float2-columns.
// Wave w scans chunk [128w, min(128w+127,1022)] with zero carry (partials -> out),
// chunk aggregates combine through LDS, then each wave fixes up its own chunk:
//   out[t] += g^(t_hi+1-t) * K_w   (K_w = true carry into chunk w; K_7 == 0)
// 256 blocks = 1 block/CU. Round-2 lesson: compiler crushed VGPRs to 32 and
// serialized load batches (2.2 TB/s). Fix: __launch_bounds__(512,2) (VGPR cap
// 256) + explicit software pipeline with prefetch regs live across backedge.
// Fix-up runs FORWARD in t (most recently written partials re-read first).

#define T_OUT 1023
#define B2    16384          // 32768 floats / 2 per lane
#define NW    8              // waves (= chunks) per block
#define S_CH  128            // chunk length (last chunk: 127)

#define GAMMA_F 0.99f
#define GL_F    0.9405f      // (float)(0.99*0.95)
#define INVG_F  1.0632642212653909f   // 1/0.9405

#define STEP2(r, v)                                \
  p.x = (r).x + GAMMA_F * vn.x - (v).x + GL_F * p.x; \
  p.y = (r).y + GAMMA_F * vn.y - (v).y + GL_F * p.y;

__global__ __launch_bounds__(512, 2) void gae_fused(
    const float2* __restrict__ r2, const float2* __restrict__ v2,
    float2* __restrict__ o2, float gS_full, float gS_last) {
  __shared__ float2 aggs[NW][64];

  const int lane = threadIdx.x & 63;
  const int w    = threadIdx.x >> 6;              // wave id == chunk id (uniform)
  const int q    = blockIdx.x * 64 + lane;        // float2 column index

  const int t_lo = w * S_CH;
  const int t_hi = (w == NW - 1) ? (T_OUT - 1) : (t_lo + S_CH - 1);

  const float2* rp = r2 + q;
  const float2* vp = v2 + q;
  float2*       op = o2 + q;

  // ---------------- phase 1: zero-carry partial scan (backward) ----------------
  float2 vn = vp[(t_hi + 1) * B2];
  float2 p  = make_float2(0.f, 0.f);

  int t = t_hi;
  const int pre = (t_hi - t_lo + 1) & 3;          // 0 for chunks 0..6, 3 for chunk 7
  for (int k = 0; k < pre; ++k, --t) {
    float2 r = rp[t * B2];
    float2 v = vp[t * B2];
    STEP2(r, v)
    op[t * B2] = p;
    vn = v;
  }

  // remaining length is a multiple of 4; software-pipelined quads
  {
    float2 rc[4], vc[4];
#pragma unroll
    for (int k = 0; k < 4; ++k) { rc[k] = rp[(t - k) * B2]; vc[k] = vp[(t - k) * B2]; }
    for (; t - 4 >= t_lo + 3; t -= 4) {
      float2 rn_[4], vn_[4];
#pragma unroll
      for (int k = 0; k < 4; ++k) { rn_[k] = rp[(t - 4 - k) * B2]; vn_[k] = vp[(t - 4 - k) * B2]; }
#pragma unroll
      for (int k = 0; k < 4; ++k) {
        STEP2(rc[k], vc[k])
        op[(t - k) * B2] = p;
        vn = vc[k];
      }
#pragma unroll
      for (int k = 0; k < 4; ++k) { rc[k] = rn_[k]; vc[k] = vn_[k]; }
    }
#pragma unroll
    for (int k = 0; k < 4; ++k) {
      STEP2(rc[k], vc[k])
      op[(t - k) * B2] = p;
      vn = vc[k];
    }
  }

  // ---------------- phase 2: combine chunk aggregates via LDS ----------------
  aggs[w][lane] = p;
  __syncthreads();

  float2 K = make_float2(0.f, 0.f);
  for (int j = NW - 1; j > w; --j) {              // wave-uniform trip count
    const float gj = (j == NW - 1) ? gS_last : gS_full;
    float2 a = aggs[j][lane];
    K.x = a.x + gj * K.x;
    K.y = a.y + gj * K.y;
  }

  // ---------------- phase 3: fix-up own chunk (forward, cache-hot first) ------
  if (w < NW - 1) {                               // chunk 7: K == 0, skip
    // x(t) = g^(t_hi+1-t) * K; at t_lo that is g^128 * K, then *= 1/g going up.
    float2 x = make_float2(gS_full * K.x, gS_full * K.y);
    int u = t_lo;                                 // len = 128, multiple of 4
    float2 oc[4];
#pragma unroll
    for (int k = 0; k < 4; ++k) oc[k] = op[(u + k) * B2];
    for (; u + 4 <= t_hi - 3; u += 4) {
      float2 on_[4];
#pragma unroll
      for (int k = 0; k < 4; ++k) on_[k] = op[(u + 4 + k) * B2];
#pragma unroll
      for (int k = 0; k < 4; ++k) {
        oc[k].x += x.x; oc[k].y += x.y;
        op[(u + k) * B2] = oc[k];
        x.x *= INVG_F;  x.y *= INVG_F;
      }
#pragma unroll
      for (int k = 0; k < 4; ++k) oc[k] = on_[k];
    }
#pragma unroll
    for (int k = 0; k < 4; ++k) {
      oc[k].x += x.x; oc[k].y += x.y;
      op[(u + k) * B2] = oc[k];
      x.x *= INVG_F;  x.y *= INVG_F;
    }
  }
}

extern "C" void kernel_launch(void* const* d_in, const int* in_sizes, int n_in,
                              void* d_out, int out_size, void* d_ws, size_t ws_size,
                              hipStream_t stream) {
  const float2* r2 = (const float2*)d_in[0];
  const float2* v2 = (const float2*)d_in[1];
  float2* o2 = (float2*)d_out;

  const double g = (double)GL_F;
  const float gS_full = (float)pow(g, 128);   // chunks 0..6
  const float gS_last = (float)pow(g, 127);   // chunk 7 (127 rows)

  // 16384 float2 cols / 64 lanes = 256 blocks -> exactly 1 block (8 waves) per CU.
  gae_fused<<<dim3(B2 / 64), dim3(512), 0, stream>>>(r2, v2, o2, gS_full, gS_last);
}